// Round 6
// baseline (68.677 us; speedup 1.0000x reference)
//
#include <hip/hip_runtime.h>

// Problem dims (fixed by the reference)
#define B_ 1024
#define O_ 256
#define I_ 256
#define S_ 20            // segments; breakpoints/values have S_+1 = 21 entries
#define SP 24            // padded slots per input-feature group (21 used + 3 zero)
#define K_ (I_ * SP)     // 6144 = GEMM K, = 192 K32-steps
#define KSPLIT 16        // K-split factor -> grid 16 mtiles x 16 kchunks
#define KSTEPS (K_ / 32 / KSPLIT)   // 12 MFMA-K steps per block

typedef unsigned int uint32;
typedef __attribute__((ext_vector_type(8))) short bf16x8;
typedef __attribute__((ext_vector_type(4))) float f32x4;

// round-to-nearest-even f32 -> bf16 bits
__device__ inline uint32 f2bf(float f) {
    uint32 u = __float_as_uint(f);
    u = (u + 0x7FFFu + ((u >> 16) & 1u)) >> 16;
    return u & 0xFFFFu;
}

// ---------------------------------------------------------------------------
// Kernel 1: build sparse weight matrix Wmat[B][K_] bf16.
// Per (b,i): faithful searchsorted(right)-1 on actual breakpoint bits,
// t=(x-lo)/(hi-lo+1e-8), zeroed outside [lo,hi). Group i occupies slots
// i*SP .. i*SP+23: w0 at s=k, w1 at s=k+1 (k<=19 -> k+1<=20), rest 0.
// Static-index word building (no scratch), 3x uint4 coalesced stores.
// ---------------------------------------------------------------------------
__global__ __launch_bounds__(256) void build_w(const float* __restrict__ x,
                                               const float* __restrict__ bp,
                                               uint32* __restrict__ wmat) {
    int idx = blockIdx.x * 256 + threadIdx.x;   // b*I + i
    float xv = x[idx];

    float bpr[S_ + 1];
#pragma unroll
    for (int s = 0; s <= S_; ++s) bpr[s] = bp[s];   // same grid for every (o,i)

    int k = -1;
#pragma unroll
    for (int s = 0; s <= S_; ++s) k += (bpr[s] <= xv) ? 1 : 0;
    k = min(max(k, 0), S_ - 1);

    float lo = bpr[k];
    float hi = bpr[k + 1];
    float t = (xv - lo) / (hi - lo + 1e-8f);
    bool inb = (xv >= lo) && (xv < hi);
    uint32 bw0 = f2bf(inb ? (1.0f - t) : 0.0f);
    uint32 bw1 = f2bf(inb ? t : 0.0f);

    uint32 u[12];
#pragma unroll
    for (int j = 0; j < 12; ++j) {
        int s0 = 2 * j, s1 = 2 * j + 1;
        uint32 lo16 = (s0 == k) ? bw0 : ((s0 == k + 1) ? bw1 : 0u);
        uint32 hi16 = (s1 == k) ? bw0 : ((s1 == k + 1) ? bw1 : 0u);
        u[j] = lo16 | (hi16 << 16);
    }
    uint4* dst = (uint4*)(wmat + (size_t)idx * 12);   // 48 B per (b,i), 16B-aligned
    dst[0] = make_uint4(u[0], u[1], u[2], u[3]);
    dst[1] = make_uint4(u[4], u[5], u[6], u[7]);
    dst[2] = make_uint4(u[8], u[9], u[10], u[11]);
}

// ---------------------------------------------------------------------------
// Kernel 2: build Vo[O][K_] bf16, o-major ("B^T" layout): group i slots
// i*SP+s = bf16(values[o][i][s]) for s<=20, 0 for s=21..23.
// ---------------------------------------------------------------------------
__global__ __launch_bounds__(256) void build_vo(const float* __restrict__ values,
                                                uint32* __restrict__ vo) {
    int idx = blockIdx.x * 256 + threadIdx.x;   // o*I + i
    const float* src = values + (size_t)idx * (S_ + 1);
    float v[S_ + 1];
#pragma unroll
    for (int s = 0; s <= S_; ++s) v[s] = src[s];

    uint32 u[12];
#pragma unroll
    for (int j = 0; j < 12; ++j) {
        int s0 = 2 * j, s1 = 2 * j + 1;
        uint32 lo16 = (s0 <= S_) ? f2bf(v[s0 <= S_ ? s0 : 0]) : 0u;
        uint32 hi16 = (s1 <= S_) ? f2bf(v[s1 <= S_ ? s1 : 0]) : 0u;
        u[j] = lo16 | (hi16 << 16);
    }
    uint4* dst = (uint4*)(vo + (size_t)idx * 12);
    dst[0] = make_uint4(u[0], u[1], u[2], u[3]);
    dst[1] = make_uint4(u[4], u[5], u[6], u[7]);
    dst[2] = make_uint4(u[8], u[9], u[10], u[11]);
}

// ---------------------------------------------------------------------------
// Kernel 3: GEMM part[kc] += Wmat[64-row tile, K-chunk] x Vo^T, no LDS.
// grid = 256 blocks = 16 mtiles x 16 kchunks; block = (64,4) = 4 waves.
// Wave wv owns rows m0..m0+15 x all 256 cols: acc = 16 n-frags (64 VGPR).
// XCD affinity: kc = (L&7)*2 + ((L>>3)&1)  -> each XCD serves 2 kchunks,
// so its 2x192KB Vo slice is L2-resident (bijective decode, mt = L>>4).
// A-frag: lane l reads W[(m0 + (l&15))][k0 + (l>>4)*8 .. +7]  (16 B).
// B-frag: lane l reads Vo[(nf*16 + (l&15))][k0 + (l>>4)*8 .. +7] (16 B).
// mfma_f32_16x16x32_bf16; C/D: col=lane&15, row=(lane>>4)*4+reg (m89).
// ---------------------------------------------------------------------------
__global__ __launch_bounds__(256, 1) void kan_gemm(const ushort* __restrict__ wmat,
                                                   const ushort* __restrict__ vo,
                                                   float* __restrict__ part) {
    int L = blockIdx.x;
    int kc = (L & 7) * 2 + ((L >> 3) & 1);
    int mt = L >> 4;
    int wv = threadIdx.y;        // 0..3
    int l  = threadIdx.x;        // 0..63
    int lr = l & 15;
    int lg = l >> 4;

    int m0 = mt * 64 + wv * 16;
    int k0 = kc * (K_ / KSPLIT);          // 384

    const ushort* aptr = wmat + (size_t)(m0 + lr) * K_ + k0 + lg * 8;
    const ushort* bptr = vo   + (size_t)lr * K_        + k0 + lg * 8;

    f32x4 acc[16] = {};
#pragma unroll
    for (int st = 0; st < KSTEPS; ++st) {
        bf16x8 a = *(const bf16x8*)(aptr + st * 32);
#pragma unroll
        for (int nf = 0; nf < 16; ++nf) {
            bf16x8 b = *(const bf16x8*)(bptr + (size_t)nf * 16 * K_ + st * 32);
            acc[nf] = __builtin_amdgcn_mfma_f32_16x16x32_bf16(a, b, acc[nf], 0, 0, 0);
        }
    }

    // store partials: part[kc][m0 + lg*4 + r][nf*16 + lr]
    float* pbase = part + ((size_t)kc << 18) + (size_t)(m0 + lg * 4) * O_ + lr;
#pragma unroll
    for (int nf = 0; nf < 16; ++nf) {
#pragma unroll
        for (int r = 0; r < 4; ++r) {
            pbase[(size_t)r * O_ + nf * 16] = acc[nf][r];
        }
    }
}

// ---------------------------------------------------------------------------
// Kernel 4: out[b][o] = sum over KSPLIT partial chunks. float4-vectorized.
// ---------------------------------------------------------------------------
__global__ __launch_bounds__(256) void kan_reduce(const float4* __restrict__ part,
                                                  float4* __restrict__ out) {
    int idx = blockIdx.x * 256 + threadIdx.x;   // over B*O/4 = 65536
    const int Q = B_ * O_ / 4;
    float4 s = part[idx];
#pragma unroll
    for (int c = 1; c < KSPLIT; ++c) {
        float4 a = part[(size_t)c * Q + idx];
        s.x += a.x; s.y += a.y; s.z += a.z; s.w += a.w;
    }
    out[idx] = s;
}

extern "C" void kernel_launch(void* const* d_in, const int* in_sizes, int n_in,
                              void* d_out, int out_size, void* d_ws, size_t ws_size,
                              hipStream_t stream) {
    const float* x      = (const float*)d_in[0];  // [B, I]
    const float* bps    = (const float*)d_in[1];  // [O, I, S+1] (uniform grid)
    const float* values = (const float*)d_in[2];  // [O, I, S+1]
    float* out = (float*)d_out;                   // [B, O]

    // Workspace carve-up (bytes):
    //   Wmat: B*K_*2       = 12,582,912
    //   Vo  : O*K_*2       =  3,145,728
    //   part: KSPLIT*B*O*4 = 16,777,216   -> total 32.5 MB
    char* ws = (char*)d_ws;
    uint32* wmat = (uint32*)(ws);
    uint32* vo   = (uint32*)(ws + (size_t)B_ * K_ * 2);
    float*  part = (float*)(ws + (size_t)B_ * K_ * 2 + (size_t)O_ * K_ * 2);

    build_w<<<dim3(B_ * I_ / 256), dim3(256), 0, stream>>>(x, bps, wmat);
    build_vo<<<dim3(O_ * I_ / 256), dim3(256), 0, stream>>>(values, vo);
    kan_gemm<<<dim3(256), dim3(64, 4), 0, stream>>>((const ushort*)wmat,
                                                    (const ushort*)vo, part);
    kan_reduce<<<dim3(B_ * O_ / 4 / 256), dim3(256), 0, stream>>>((const float4*)part,
                                                                  (float4*)out);
}

// Round 7
// 53.170 us; speedup vs baseline: 1.2917x; 1.2917x over previous
//
#include <hip/hip_runtime.h>

// Problem dims (fixed by the reference)
#define B_ 1024
#define O_ 256
#define I_ 256
#define S_ 20            // segments; breakpoints/values have S_+1 = 21 entries
#define SP 24            // padded slots per input-feature group (21 used + 3 zero)
#define K_ (I_ * SP)     // 6144 = GEMM K
#define KSPLIT 16        // K-split -> kchunk = 384 = 12 MFMA-K steps
#define KCH (K_ / KSPLIT)
#define KSTEPS (KCH / 32)

typedef unsigned int uint32;
typedef __attribute__((ext_vector_type(8))) short bf16x8;
typedef __attribute__((ext_vector_type(4))) float f32x4;

// round-to-nearest-even f32 -> bf16 bits
__device__ inline uint32 f2bf(float f) {
    uint32 u = __float_as_uint(f);
    u = (u + 0x7FFFu + ((u >> 16) & 1u)) >> 16;
    return u & 0xFFFFu;
}

// ---------------------------------------------------------------------------
// Kernel 1: build sparse weight matrix Wmat[B][K_] bf16.
// Per (b,i): faithful searchsorted(right)-1 on actual breakpoint bits,
// t=(x-lo)/(hi-lo+1e-8), zeroed outside [lo,hi). Group i occupies slots
// i*SP..i*SP+23: w0 at s=k, w1 at s=k+1, rest 0.
// ---------------------------------------------------------------------------
__global__ __launch_bounds__(256) void build_w(const float* __restrict__ x,
                                               const float* __restrict__ bp,
                                               uint32* __restrict__ wmat) {
    int idx = blockIdx.x * 256 + threadIdx.x;   // b*I + i
    float xv = x[idx];

    float bpr[S_ + 1];
#pragma unroll
    for (int s = 0; s <= S_; ++s) bpr[s] = bp[s];   // same grid for every (o,i)

    int k = -1;
#pragma unroll
    for (int s = 0; s <= S_; ++s) k += (bpr[s] <= xv) ? 1 : 0;
    k = min(max(k, 0), S_ - 1);

    float lo = bpr[k];
    float hi = bpr[k + 1];
    float t = (xv - lo) / (hi - lo + 1e-8f);
    bool inb = (xv >= lo) && (xv < hi);
    uint32 bw0 = f2bf(inb ? (1.0f - t) : 0.0f);
    uint32 bw1 = f2bf(inb ? t : 0.0f);

    uint32 u[12];
#pragma unroll
    for (int j = 0; j < 12; ++j) {
        int s0 = 2 * j, s1 = 2 * j + 1;
        uint32 lo16 = (s0 == k) ? bw0 : ((s0 == k + 1) ? bw1 : 0u);
        uint32 hi16 = (s1 == k) ? bw0 : ((s1 == k + 1) ? bw1 : 0u);
        u[j] = lo16 | (hi16 << 16);
    }
    uint4* dst = (uint4*)(wmat + (size_t)idx * 12);   // 48 B per (b,i)
    dst[0] = make_uint4(u[0], u[1], u[2], u[3]);
    dst[1] = make_uint4(u[4], u[5], u[6], u[7]);
    dst[2] = make_uint4(u[8], u[9], u[10], u[11]);
}

// ---------------------------------------------------------------------------
// Kernel 2: build Vo[O][K_] bf16, o-major ("B^T" layout): slot i*SP+s =
// bf16(values[o][i][s]) for s<=20, 0 for s=21..23.
// ---------------------------------------------------------------------------
__global__ __launch_bounds__(256) void build_vo(const float* __restrict__ values,
                                                uint32* __restrict__ vo) {
    int idx = blockIdx.x * 256 + threadIdx.x;   // o*I + i
    const float* src = values + (size_t)idx * (S_ + 1);
    float v[S_ + 1];
#pragma unroll
    for (int s = 0; s <= S_; ++s) v[s] = src[s];

    uint32 u[12];
#pragma unroll
    for (int j = 0; j < 12; ++j) {
        int s0 = 2 * j, s1 = 2 * j + 1;
        uint32 lo16 = (s0 <= S_) ? f2bf(v[s0 <= S_ ? s0 : 0]) : 0u;
        uint32 hi16 = (s1 <= S_) ? f2bf(v[s1 <= S_ ? s1 : 0]) : 0u;
        u[j] = lo16 | (hi16 << 16);
    }
    uint4* dst = (uint4*)(vo + (size_t)idx * 12);
    dst[0] = make_uint4(u[0], u[1], u[2], u[3]);
    dst[1] = make_uint4(u[4], u[5], u[6], u[7]);
    dst[2] = make_uint4(u[8], u[9], u[10], u[11]);
}

// ---------------------------------------------------------------------------
// Kernel 3: GEMM, re-scheduled for occupancy (R6 was 1 wave/SIMD, latency-
// bound at MfmaUtil 2.3%). grid = 1024 blocks = 16 kc x 16 mt x 4 nt ->
// 4 blocks/CU, 16 waves/CU. Wave tile 16 rows x 64 cols: acc = 4 n-frags
// (16 VGPR), per K-step 1 A-load + 4 B-loads, fully unrolled (60 loads in
// flight across 12 steps). XCD affinity kc = (L&7)*2+((L>>3)&1): per-XCD
// set = 2 kchunks x (A 768KB + B 192KB) < 4MiB L2.
// Verified mapping (R6, absmax ok): A lane l = W[m0+(l&15)][k0+(l>>4)*8..+7],
// B lane l = Vo[n0+(l&15)][same k]; C/D col=lane&15, row=(lane>>4)*4+reg.
// ---------------------------------------------------------------------------
__global__ __launch_bounds__(256, 4) void kan_gemm(const ushort* __restrict__ wmat,
                                                   const ushort* __restrict__ vo,
                                                   float* __restrict__ part) {
    int L = blockIdx.x;                   // 0..1023
    int kc = (L & 7) * 2 + ((L >> 3) & 1);
    int mt = (L >> 4) & 15;
    int nt = L >> 8;                      // 0..3
    int wv = threadIdx.y;                 // 0..3
    int l  = threadIdx.x;                 // 0..63
    int lr = l & 15;
    int lg = l >> 4;

    int m0 = mt * 64 + wv * 16;
    int n0 = nt * 64;
    int k0 = kc * KCH;

    const ushort* aptr = wmat + (size_t)(m0 + lr) * K_ + k0 + lg * 8;
    const ushort* bptr = vo   + (size_t)(n0 + lr) * K_ + k0 + lg * 8;

    f32x4 acc[4] = {};
#pragma unroll
    for (int st = 0; st < KSTEPS; ++st) {
        bf16x8 a = *(const bf16x8*)(aptr + st * 32);
#pragma unroll
        for (int nf = 0; nf < 4; ++nf) {
            bf16x8 b = *(const bf16x8*)(bptr + (size_t)nf * 16 * K_ + st * 32);
            acc[nf] = __builtin_amdgcn_mfma_f32_16x16x32_bf16(a, b, acc[nf], 0, 0, 0);
        }
    }

    // store partials: part[kc][m0 + lg*4 + r][n0 + nf*16 + lr]
    float* pbase = part + ((size_t)kc << 18) + (size_t)(m0 + lg * 4) * O_ + n0 + lr;
#pragma unroll
    for (int nf = 0; nf < 4; ++nf) {
#pragma unroll
        for (int r = 0; r < 4; ++r) {
            pbase[(size_t)r * O_ + nf * 16] = acc[nf][r];
        }
    }
}

// ---------------------------------------------------------------------------
// Kernel 4: out[b][o] = sum over KSPLIT partial chunks. float4-vectorized.
// ---------------------------------------------------------------------------
__global__ __launch_bounds__(256) void kan_reduce(const float4* __restrict__ part,
                                                  float4* __restrict__ out) {
    int idx = blockIdx.x * 256 + threadIdx.x;   // over B*O/4 = 65536
    const int Q = B_ * O_ / 4;
    float4 s = part[idx];
#pragma unroll
    for (int c = 1; c < KSPLIT; ++c) {
        float4 a = part[(size_t)c * Q + idx];
        s.x += a.x; s.y += a.y; s.z += a.z; s.w += a.w;
    }
    out[idx] = s;
}

extern "C" void kernel_launch(void* const* d_in, const int* in_sizes, int n_in,
                              void* d_out, int out_size, void* d_ws, size_t ws_size,
                              hipStream_t stream) {
    const float* x      = (const float*)d_in[0];  // [B, I]
    const float* bps    = (const float*)d_in[1];  // [O, I, S+1] (uniform grid)
    const float* values = (const float*)d_in[2];  // [O, I, S+1]
    float* out = (float*)d_out;                   // [B, O]

    // Workspace carve-up (bytes):
    //   Wmat: B*K_*2       = 12,582,912
    //   Vo  : O*K_*2       =  3,145,728
    //   part: KSPLIT*B*O*4 = 16,777,216   -> total 32.5 MB
    char* ws = (char*)d_ws;
    uint32* wmat = (uint32*)(ws);
    uint32* vo   = (uint32*)(ws + (size_t)B_ * K_ * 2);
    float*  part = (float*)(ws + (size_t)B_ * K_ * 2 + (size_t)O_ * K_ * 2);

    build_w<<<dim3(B_ * I_ / 256), dim3(256), 0, stream>>>(x, bps, wmat);
    build_vo<<<dim3(O_ * I_ / 256), dim3(256), 0, stream>>>(values, vo);
    kan_gemm<<<dim3(1024), dim3(64, 4), 0, stream>>>((const ushort*)wmat,
                                                     (const ushort*)vo, part);
    kan_reduce<<<dim3(B_ * O_ / 4 / 256), dim3(256), 0, stream>>>((const float4*)part,
                                                                  (float4*)out);
}

// Round 8
// 44.127 us; speedup vs baseline: 1.5564x; 1.2049x over previous
//
#include <hip/hip_runtime.h>

// Problem dims (fixed by the reference)
#define B_ 1024
#define O_ 256
#define I_ 256
#define S_ 20            // segments; breakpoints/values have S_+1 = 21 entries
#define SP 24            // padded slots per input-feature group (21 used + 3 zero)
#define K_ (I_ * SP)     // 6144 = GEMM K
#define KSPLIT 16        // K-split -> kchunk = 384 = 6 BK64 steps
#define KCH (K_ / KSPLIT)
#define NSTEP (KCH / 64) // 6

typedef unsigned int uint32;
typedef __attribute__((ext_vector_type(8))) short bf16x8;
typedef __attribute__((ext_vector_type(4))) float f32x4;

// round-to-nearest-even f32 -> bf16 bits
__device__ inline uint32 f2bf(float f) {
    uint32 u = __float_as_uint(f);
    u = (u + 0x7FFFu + ((u >> 16) & 1u)) >> 16;
    return u & 0xFFFFu;
}

// ---------------------------------------------------------------------------
// Kernel 1: build sparse weight matrix Wmat[B][K_] bf16 (verified R6/R7).
// ---------------------------------------------------------------------------
__global__ __launch_bounds__(256) void build_w(const float* __restrict__ x,
                                               const float* __restrict__ bp,
                                               uint32* __restrict__ wmat) {
    int idx = blockIdx.x * 256 + threadIdx.x;   // b*I + i
    float xv = x[idx];

    float bpr[S_ + 1];
#pragma unroll
    for (int s = 0; s <= S_; ++s) bpr[s] = bp[s];

    int k = -1;
#pragma unroll
    for (int s = 0; s <= S_; ++s) k += (bpr[s] <= xv) ? 1 : 0;
    k = min(max(k, 0), S_ - 1);

    float lo = bpr[k];
    float hi = bpr[k + 1];
    float t = (xv - lo) / (hi - lo + 1e-8f);
    bool inb = (xv >= lo) && (xv < hi);
    uint32 bw0 = f2bf(inb ? (1.0f - t) : 0.0f);
    uint32 bw1 = f2bf(inb ? t : 0.0f);

    uint32 u[12];
#pragma unroll
    for (int j = 0; j < 12; ++j) {
        int s0 = 2 * j, s1 = 2 * j + 1;
        uint32 lo16 = (s0 == k) ? bw0 : ((s0 == k + 1) ? bw1 : 0u);
        uint32 hi16 = (s1 == k) ? bw0 : ((s1 == k + 1) ? bw1 : 0u);
        u[j] = lo16 | (hi16 << 16);
    }
    uint4* dst = (uint4*)(wmat + (size_t)idx * 12);
    dst[0] = make_uint4(u[0], u[1], u[2], u[3]);
    dst[1] = make_uint4(u[4], u[5], u[6], u[7]);
    dst[2] = make_uint4(u[8], u[9], u[10], u[11]);
}

// ---------------------------------------------------------------------------
// Kernel 2: build Vo[O][K_] bf16, o-major (verified R6/R7).
// ---------------------------------------------------------------------------
__global__ __launch_bounds__(256) void build_vo(const float* __restrict__ values,
                                                uint32* __restrict__ vo) {
    int idx = blockIdx.x * 256 + threadIdx.x;   // o*I + i
    const float* src = values + (size_t)idx * (S_ + 1);
    float v[S_ + 1];
#pragma unroll
    for (int s = 0; s <= S_; ++s) v[s] = src[s];

    uint32 u[12];
#pragma unroll
    for (int j = 0; j < 12; ++j) {
        int s0 = 2 * j, s1 = 2 * j + 1;
        uint32 lo16 = (s0 <= S_) ? f2bf(v[s0 <= S_ ? s0 : 0]) : 0u;
        uint32 hi16 = (s1 <= S_) ? f2bf(v[s1 <= S_ ? s1 : 0]) : 0u;
        u[j] = lo16 | (hi16 << 16);
    }
    uint4* dst = (uint4*)(vo + (size_t)idx * 12);
    dst[0] = make_uint4(u[0], u[1], u[2], u[3]);
    dst[1] = make_uint4(u[4], u[5], u[6], u[7]);
    dst[2] = make_uint4(u[8], u[9], u[10], u[11]);
}

// ---------------------------------------------------------------------------
// Kernel 3: LDS-staged GEMM. Every no-LDS variant plateaued at 7-12 TB/s of
// L2/L3 re-reads (R1-R7); LDS staging cuts block traffic 245MB -> ~50MB.
// grid = 512 = 16 kc x 16 mt x 2 nt (bijective, kc XCD-affine: per-XCD
// slices A 1.57MB + B 0.39MB, L2-resident). block = (64,4) = 4 waves,
// 2 blocks/CU -> 8 waves/CU. Tiles: A[64][64] B[128][64] bf16 in LDS,
// T2 XOR-swizzled (byte ^= (row&7)<<4) -> conflict-free-ish b128 access.
// Wave w: rows wm*32..+31, cols wn*64..+63 (wm=w&1, wn=w>>1); acc 2x4 frags.
// Reg double-buffered staging: LOAD(s+1) issued right after STORE(s), so
// global latency hides under COMPUTE(s).
// Verified frag maps (R6/R7 absmax ok): A lane l = row m0+(l&15),
// k (l>>4)*8..+7 (+32 for kk=1); B same with col; C/D col=l&15,
// row=(l>>4)*4+reg.
// ---------------------------------------------------------------------------
__global__ __launch_bounds__(256, 2) void kan_gemm(const ushort* __restrict__ wmat,
                                                   const ushort* __restrict__ vo,
                                                   float* __restrict__ part) {
    __shared__ ushort Als[64 * 64];    // 8 KB   [row][k] swizzled
    __shared__ ushort Bls[128 * 64];   // 16 KB

    int L = blockIdx.x;                    // 0..511
    int kc = (L & 7) * 2 + ((L >> 3) & 1); // XCD-affine, bijective
    int mt = (L >> 4) & 15;
    int nt = (L >> 8) & 1;
    int l = threadIdx.x, w = threadIdx.y;
    int t = w * 64 + l;
    int wm = w & 1, wn = w >> 1;
    int lr = l & 15, lg = l >> 4;

    int bm0 = mt * 64, bn0 = nt * 128;
    int k0 = kc * KCH;

    // ---- staging addresses: thread t owns 16B slot (row=t>>3 [+32j], slot=t&7)
    int srow = t >> 3, sslot = t & 7;
    const int R4 = K_ / 8;  // uint4 per global row = 768
    const uint4* agp = (const uint4*)(wmat + (size_t)(bm0 + srow) * K_ + k0) + sslot;
    const uint4* bgp = (const uint4*)(vo   + (size_t)(bn0 + srow) * K_ + k0) + sslot;
    int sw = ((sslot ^ (srow & 7)) << 4);          // swizzled byte slot
    char* awr = (char*)Als + srow * 128 + sw;      // rows +32 share (row&7)
    char* bwr = (char*)Bls + srow * 128 + sw;

    // ---- fragment byte offsets (kk=0); kk=1 applies ^64 (bit6 above XOR ok)
    int xorr = (lr & 7) << 4;
    int kb = (lg << 4) ^ xorr;
    int aoff0 = (wm * 32 + 0  + lr) * 128 + kb;
    int aoff1 = (wm * 32 + 16 + lr) * 128 + kb;
    int boff0 = (wn * 64 + 0  + lr) * 128 + kb;
    int boff1 = (wn * 64 + 16 + lr) * 128 + kb;
    int boff2 = (wn * 64 + 32 + lr) * 128 + kb;
    int boff3 = (wn * 64 + 48 + lr) * 128 + kb;

    f32x4 acc[2][4] = {};

#define LOADT(RA, RB, S) do { \
        RA[0] = agp[(S)*8];               RA[1] = agp[(S)*8 + 32*R4]; \
        RB[0] = bgp[(S)*8];               RB[1] = bgp[(S)*8 + 32*R4]; \
        RB[2] = bgp[(S)*8 + 64*R4];       RB[3] = bgp[(S)*8 + 96*R4]; \
    } while (0)

#define STORET(RA, RB) do { \
        *(uint4*)(awr)          = RA[0];  *(uint4*)(awr + 4096)  = RA[1]; \
        *(uint4*)(bwr)          = RB[0];  *(uint4*)(bwr + 4096)  = RB[1]; \
        *(uint4*)(bwr + 8192)   = RB[2];  *(uint4*)(bwr + 12288) = RB[3]; \
    } while (0)

#define COMPUTET() do { \
        _Pragma("unroll") \
        for (int kk = 0; kk < 2; ++kk) { \
            int kx = kk << 6; \
            bf16x8 a0 = *(const bf16x8*)((const char*)Als + (aoff0 ^ kx)); \
            bf16x8 a1 = *(const bf16x8*)((const char*)Als + (aoff1 ^ kx)); \
            bf16x8 b0 = *(const bf16x8*)((const char*)Bls + (boff0 ^ kx)); \
            bf16x8 b1 = *(const bf16x8*)((const char*)Bls + (boff1 ^ kx)); \
            bf16x8 b2 = *(const bf16x8*)((const char*)Bls + (boff2 ^ kx)); \
            bf16x8 b3 = *(const bf16x8*)((const char*)Bls + (boff3 ^ kx)); \
            acc[0][0] = __builtin_amdgcn_mfma_f32_16x16x32_bf16(a0, b0, acc[0][0], 0, 0, 0); \
            acc[0][1] = __builtin_amdgcn_mfma_f32_16x16x32_bf16(a0, b1, acc[0][1], 0, 0, 0); \
            acc[0][2] = __builtin_amdgcn_mfma_f32_16x16x32_bf16(a0, b2, acc[0][2], 0, 0, 0); \
            acc[0][3] = __builtin_amdgcn_mfma_f32_16x16x32_bf16(a0, b3, acc[0][3], 0, 0, 0); \
            acc[1][0] = __builtin_amdgcn_mfma_f32_16x16x32_bf16(a1, b0, acc[1][0], 0, 0, 0); \
            acc[1][1] = __builtin_amdgcn_mfma_f32_16x16x32_bf16(a1, b1, acc[1][1], 0, 0, 0); \
            acc[1][2] = __builtin_amdgcn_mfma_f32_16x16x32_bf16(a1, b2, acc[1][2], 0, 0, 0); \
            acc[1][3] = __builtin_amdgcn_mfma_f32_16x16x32_bf16(a1, b3, acc[1][3], 0, 0, 0); \
        } \
    } while (0)

    uint4 rA0[2], rB0[4], rA1[2], rB1[4];
    LOADT(rA0, rB0, 0);
    // s=0
    STORET(rA0, rB0); LOADT(rA1, rB1, 1); __syncthreads(); COMPUTET();
    // s=1
    __syncthreads(); STORET(rA1, rB1); LOADT(rA0, rB0, 2); __syncthreads(); COMPUTET();
    // s=2
    __syncthreads(); STORET(rA0, rB0); LOADT(rA1, rB1, 3); __syncthreads(); COMPUTET();
    // s=3
    __syncthreads(); STORET(rA1, rB1); LOADT(rA0, rB0, 4); __syncthreads(); COMPUTET();
    // s=4
    __syncthreads(); STORET(rA0, rB0); LOADT(rA1, rB1, 5); __syncthreads(); COMPUTET();
    // s=5
    __syncthreads(); STORET(rA1, rB1); __syncthreads(); COMPUTET();

#undef LOADT
#undef STORET
#undef COMPUTET

    // ---- epilogue: part[kc][bm0+wm*32+mi*16+lg*4+r][bn0+wn*64+ni*16+lr]
    float* pb = part + ((size_t)kc << 18) + (size_t)(bm0 + wm * 32 + lg * 4) * O_
              + bn0 + wn * 64 + lr;
#pragma unroll
    for (int mi = 0; mi < 2; ++mi) {
#pragma unroll
        for (int ni = 0; ni < 4; ++ni) {
#pragma unroll
            for (int r = 0; r < 4; ++r) {
                pb[(size_t)(mi * 16 + r) * O_ + ni * 16] = acc[mi][ni][r];
            }
        }
    }
}

// ---------------------------------------------------------------------------
// Kernel 4: out[b][o] = sum over KSPLIT partial chunks. float4-vectorized.
// ---------------------------------------------------------------------------
__global__ __launch_bounds__(256) void kan_reduce(const float4* __restrict__ part,
                                                  float4* __restrict__ out) {
    int idx = blockIdx.x * 256 + threadIdx.x;   // over B*O/4 = 65536
    const int Q = B_ * O_ / 4;
    float4 s = part[idx];
#pragma unroll
    for (int c = 1; c < KSPLIT; ++c) {
        float4 a = part[(size_t)c * Q + idx];
        s.x += a.x; s.y += a.y; s.z += a.z; s.w += a.w;
    }
    out[idx] = s;
}

extern "C" void kernel_launch(void* const* d_in, const int* in_sizes, int n_in,
                              void* d_out, int out_size, void* d_ws, size_t ws_size,
                              hipStream_t stream) {
    const float* x      = (const float*)d_in[0];  // [B, I]
    const float* bps    = (const float*)d_in[1];  // [O, I, S+1] (uniform grid)
    const float* values = (const float*)d_in[2];  // [O, I, S+1]
    float* out = (float*)d_out;                   // [B, O]

    // Workspace carve-up (bytes):
    //   Wmat: B*K_*2       = 12,582,912
    //   Vo  : O*K_*2       =  3,145,728
    //   part: KSPLIT*B*O*4 = 16,777,216   -> total 32.5 MB
    char* ws = (char*)d_ws;
    uint32* wmat = (uint32*)(ws);
    uint32* vo   = (uint32*)(ws + (size_t)B_ * K_ * 2);
    float*  part = (float*)(ws + (size_t)B_ * K_ * 2 + (size_t)O_ * K_ * 2);

    build_w<<<dim3(B_ * I_ / 256), dim3(256), 0, stream>>>(x, bps, wmat);
    build_vo<<<dim3(O_ * I_ / 256), dim3(256), 0, stream>>>(values, vo);
    kan_gemm<<<dim3(512), dim3(64, 4), 0, stream>>>((const ushort*)wmat,
                                                    (const ushort*)vo, part);
    kan_reduce<<<dim3(B_ * O_ / 4 / 256), dim3(256), 0, stream>>>((const float4*)part,
                                                                  (float4*)out);
}

// Round 9
// 30.161 us; speedup vs baseline: 2.2770x; 1.4630x over previous
//
#include <hip/hip_runtime.h>

// Problem dims (fixed by the reference)
#define B_ 1024
#define O_ 256
#define I_ 256
#define S_ 20            // segments; breakpoints/values have S_+1 = 21 entries
#define SP 24            // padded slots per input-feature group
#define K_ (I_ * SP)     // 6144 = GEMM K
#define KSPLIT 16        // kchunk = 384 k = 16 i-groups
#define BK 96            // 4 i-groups per step
#define NSTEP 4          // 384 / 96

typedef unsigned int uint32;
typedef __attribute__((ext_vector_type(8))) short bf16x8;
typedef __attribute__((ext_vector_type(4))) float f32x4;

// round-to-nearest-even f32 -> bf16 bits
__device__ inline uint32 f2bf(float f) {
    uint32 u = __float_as_uint(f);
    u = (u + 0x7FFFu + ((u >> 16) & 1u)) >> 16;
    return u & 0xFFFFu;
}

// ---------------------------------------------------------------------------
// Kernel 1: build Vo[O][K_] bf16, o-major (verified R6-R8): slot i*SP+s =
// bf16(values[o][i][s]) for s<=20, 0 for s=21..23.
// ---------------------------------------------------------------------------
__global__ __launch_bounds__(256) void build_vo(const float* __restrict__ values,
                                                uint32* __restrict__ vo) {
    int idx = blockIdx.x * 256 + threadIdx.x;   // o*I + i
    const float* src = values + (size_t)idx * (S_ + 1);
    float v[S_ + 1];
#pragma unroll
    for (int s = 0; s <= S_; ++s) v[s] = src[s];

    uint32 u[12];
#pragma unroll
    for (int j = 0; j < 12; ++j) {
        int s0 = 2 * j, s1 = 2 * j + 1;
        uint32 lo16 = (s0 <= S_) ? f2bf(v[s0 <= S_ ? s0 : 0]) : 0u;
        uint32 hi16 = (s1 <= S_) ? f2bf(v[s1 <= S_ ? s1 : 0]) : 0u;
        u[j] = lo16 | (hi16 << 16);
    }
    uint4* dst = (uint4*)(vo + (size_t)idx * 12);
    dst[0] = make_uint4(u[0], u[1], u[2], u[3]);
    dst[1] = make_uint4(u[4], u[5], u[6], u[7]);
    dst[2] = make_uint4(u[8], u[9], u[10], u[11]);
}

// ---------------------------------------------------------------------------
// Kernel 2 (fused): A-tile built in-LDS from x (Wmat never materialized).
// grid = 1024 = 16 kc x 16 mt x 4 nt, kc XCD-affine: kc=((L&7)<<1)|((L>>3)&1).
// block = (64,4) = 4 waves, 4 blocks/CU (LDS 32KB, VGPR<=128).
// LDS tiles: [64 rows][16 slots of 16B] (12 used + 4 pad), swizzle
// slot^(row&7) -> <=2-way bank conflicts on ds_read_b128 (free, m136).
// Per step s (BK=96 = 4 i-groups):
//   A-build: thread (row=t>>2, g=t&3) computes the verified searchsorted
//     record for x[m0+row][kc*16+s*4+g] -> 12 bf16-pair words -> 3 uint4
//     LDS stores (dense, no zero-fill pass).
//   B-stage: thread (brow=t>>2, j=t&3) copies slots j, j+4, j+8 from Vo
//     (prefetched one step ahead -> latency hides under compute).
//   barrier; 3 kk x {2 A-frag + 2 B-frag ds_read_b128, 4 MFMA}; barrier.
// Wave tile 32x32: wm=w&1, wn=w>>1, acc[2][2] f32x4.
// Frag maps verified R6-R8: A lane l = row base+(l&15), k (l>>4)*8..+7;
// C/D col=l&15, row=(l>>4)*4+reg.
// ---------------------------------------------------------------------------
__global__ __launch_bounds__(256, 4) void kan_fused(const float* __restrict__ x,
                                                    const float* __restrict__ bp,
                                                    const uint4* __restrict__ vo4,
                                                    float* __restrict__ part) {
    __shared__ uint4 Als[64 * 16];   // 16 KB
    __shared__ uint4 Bls[64 * 16];   // 16 KB

    int L = blockIdx.x;                        // 0..1023
    int kc = ((L & 7) << 1) | ((L >> 3) & 1);  // XCD-affine, bijective
    int mt = (L >> 4) & 15;
    int nt = L >> 8;                           // 0..3
    int l = threadIdx.x, w = threadIdx.y;
    int t = w * 64 + l;
    int wm = w & 1, wn = w >> 1;
    int lr = l & 15, lg = l >> 4;
    int m0 = mt * 64, n0 = nt * 64;

    // breakpoints once (wave-uniform scalar loads)
    float bpr[S_ + 1];
#pragma unroll
    for (int q = 0; q <= S_; ++q) bpr[q] = bp[q];

    // A-build cell addressing
    int arow = t >> 2, ag = t & 3;
    const float* xp = x + (size_t)(m0 + arow) * I_ + kc * 16 + ag;
    uint4* awp = Als + arow * 16;
    int asw = arow & 7;

    // B staging addressing
    int brow = t >> 2, bj = t & 3;
    const uint4* bgp = vo4 + (size_t)(n0 + brow) * (K_ / 8) + kc * 48 + bj;
    uint4* bwp = Bls + brow * 16;
    int bsw = brow & 7;

    // fragment read bases
    const uint4* afr = Als + (wm * 32 + lr) * 16;
    const uint4* bfr = Bls + (wn * 32 + lr) * 16;
    int fsw = lr & 7;

    // prefetch all x (4 floats) and step-0 B slots
    float xs[NSTEP];
#pragma unroll
    for (int s = 0; s < NSTEP; ++s) xs[s] = xp[s * 4];
    uint4 nb0 = bgp[0], nb1 = bgp[4], nb2 = bgp[8];

    f32x4 acc[2][2] = {};

#pragma unroll
    for (int s = 0; s < NSTEP; ++s) {
        // ---- A build (pure VALU, overlaps B prefetch latency) ----
        float xv = xs[s];
        int k = -1;
#pragma unroll
        for (int q = 0; q <= S_; ++q) k += (bpr[q] <= xv) ? 1 : 0;
        k = min(max(k, 0), S_ - 1);
        float lo = bpr[k], hi = bpr[k + 1];
        float tt = (xv - lo) / (hi - lo + 1e-8f);
        bool inb = (xv >= lo) && (xv < hi);
        uint32 bw0 = f2bf(inb ? (1.0f - tt) : 0.0f);
        uint32 bw1 = f2bf(inb ? tt : 0.0f);
        uint32 u[12];
#pragma unroll
        for (int j = 0; j < 12; ++j) {
            int s0 = 2 * j, s1 = 2 * j + 1;
            uint32 lo16 = (s0 == k) ? bw0 : ((s0 == k + 1) ? bw1 : 0u);
            uint32 hi16 = (s1 == k) ? bw0 : ((s1 == k + 1) ? bw1 : 0u);
            u[j] = lo16 | (hi16 << 16);
        }
        awp[(3 * ag + 0) ^ asw] = make_uint4(u[0], u[1], u[2], u[3]);
        awp[(3 * ag + 1) ^ asw] = make_uint4(u[4], u[5], u[6], u[7]);
        awp[(3 * ag + 2) ^ asw] = make_uint4(u[8], u[9], u[10], u[11]);

        // ---- B store (prefetched), then prefetch next step ----
        bwp[(bj + 0) ^ bsw] = nb0;
        bwp[(bj + 4) ^ bsw] = nb1;
        bwp[(bj + 8) ^ bsw] = nb2;
        if (s < NSTEP - 1) {
            nb0 = bgp[(s + 1) * 12 + 0];
            nb1 = bgp[(s + 1) * 12 + 4];
            nb2 = bgp[(s + 1) * 12 + 8];
        }
        __syncthreads();

        // ---- compute: BK=96 = 3 kk-subtiles of 32 k ----
#pragma unroll
        for (int kk = 0; kk < 3; ++kk) {
            int sl = kk * 4 + lg;
            bf16x8 a0 = *(const bf16x8*)(afr + (sl ^ fsw));
            bf16x8 a1 = *(const bf16x8*)(afr + 16 * 16 + (sl ^ fsw));
            bf16x8 b0 = *(const bf16x8*)(bfr + (sl ^ fsw));
            bf16x8 b1 = *(const bf16x8*)(bfr + 16 * 16 + (sl ^ fsw));
            acc[0][0] = __builtin_amdgcn_mfma_f32_16x16x32_bf16(a0, b0, acc[0][0], 0, 0, 0);
            acc[0][1] = __builtin_amdgcn_mfma_f32_16x16x32_bf16(a0, b1, acc[0][1], 0, 0, 0);
            acc[1][0] = __builtin_amdgcn_mfma_f32_16x16x32_bf16(a1, b0, acc[1][0], 0, 0, 0);
            acc[1][1] = __builtin_amdgcn_mfma_f32_16x16x32_bf16(a1, b1, acc[1][1], 0, 0, 0);
        }
        __syncthreads();
    }

    // ---- epilogue: part[kc][m0+wm*32+mi*16+lg*4+r][n0+wn*32+ni*16+lr] ----
    float* pb = part + ((size_t)kc << 18)
              + (size_t)(m0 + wm * 32 + lg * 4) * O_ + n0 + wn * 32 + lr;
#pragma unroll
    for (int mi = 0; mi < 2; ++mi)
#pragma unroll
        for (int ni = 0; ni < 2; ++ni)
#pragma unroll
            for (int r = 0; r < 4; ++r)
                pb[(size_t)(mi * 16 + r) * O_ + ni * 16] = acc[mi][ni][r];
}

// ---------------------------------------------------------------------------
// Kernel 3: out[b][o] = sum over KSPLIT partial chunks. float4-vectorized.
// ---------------------------------------------------------------------------
__global__ __launch_bounds__(256) void kan_reduce(const float4* __restrict__ part,
                                                  float4* __restrict__ out) {
    int idx = blockIdx.x * 256 + threadIdx.x;   // over B*O/4 = 65536
    const int Q = B_ * O_ / 4;
    float4 s = part[idx];
#pragma unroll
    for (int c = 1; c < KSPLIT; ++c) {
        float4 a = part[(size_t)c * Q + idx];
        s.x += a.x; s.y += a.y; s.z += a.z; s.w += a.w;
    }
    out[idx] = s;
}

extern "C" void kernel_launch(void* const* d_in, const int* in_sizes, int n_in,
                              void* d_out, int out_size, void* d_ws, size_t ws_size,
                              hipStream_t stream) {
    const float* x      = (const float*)d_in[0];  // [B, I]
    const float* bps    = (const float*)d_in[1];  // [O, I, S+1] (uniform grid)
    const float* values = (const float*)d_in[2];  // [O, I, S+1]
    float* out = (float*)d_out;                   // [B, O]

    // Workspace carve-up (bytes):
    //   Vo  : O*K_*2       =  3,145,728
    //   part: KSPLIT*B*O*4 = 16,777,216   -> total 19.9 MB
    char* ws = (char*)d_ws;
    uint32* vo   = (uint32*)(ws);
    float*  part = (float*)(ws + (size_t)O_ * K_ * 2);

    build_vo<<<dim3(O_ * I_ / 256), dim3(256), 0, stream>>>(values, vo);
    kan_fused<<<dim3(1024), dim3(64, 4), 0, stream>>>(x, bps, (const uint4*)vo, part);
    kan_reduce<<<dim3(B_ * O_ / 4 / 256), dim3(256), 0, stream>>>((const float4*)part,
                                                                  (float4*)out);
}